// Round 14
// baseline (509.661 us; speedup 1.0000x reference)
//
#include <hip/hip_runtime.h>
#include <math.h>

#define NEG_SLOPE 0.2f

typedef __attribute__((ext_vector_type(8))) short short8;
typedef __attribute__((ext_vector_type(8))) unsigned short ushort8v;
typedef __attribute__((ext_vector_type(4))) float float4v;

__device__ __forceinline__ void atomAddF(float* p, float v) {
    unsafeAtomicAdd(p, v);   // HW global_atomic_add_f32 on gfx950
}
__device__ __forceinline__ unsigned short f2bf(float f) {
    unsigned u = __float_as_uint(f);
    unsigned r = (u + 0x7FFFu + ((u >> 16) & 1u)) >> 16;   // RNE
    return (unsigned short)r;
}
__device__ __forceinline__ float bf2f(unsigned short b) {
    return __uint_as_float((unsigned)b << 16);
}

// ================= CSR build: two-pass LDS-binned sort =================
__global__ void bhist_kernel(const int* __restrict__ dst, int* __restrict__ bcnt, int E) {
    __shared__ int h[256];
    int t = threadIdx.x;
    h[t] = 0;
    __syncthreads();
    for (int e = blockIdx.x * blockDim.x + t; e < E; e += gridDim.x * blockDim.x)
        atomicAdd(&h[dst[e] >> 9], 1);
    __syncthreads();
    if (h[t]) atomicAdd(&bcnt[t], h[t]);
}

__global__ void bscan_kernel(const int* __restrict__ bcnt, int* __restrict__ bbase,
                             int* __restrict__ bcursor, int NB, int* __restrict__ rowptr,
                             int n, int E) {
    __shared__ int s[256];
    int t = threadIdx.x;
    int v = (t < NB) ? bcnt[t] : 0;
    s[t] = v; __syncthreads();
    for (int o = 1; o < 256; o <<= 1) {
        int u = (t >= o) ? s[t - o] : 0;
        __syncthreads(); s[t] += u; __syncthreads();
    }
    int excl = s[t] - v;
    if (t < NB) { bbase[t] = excl; bcursor[t] = excl; }
    if (t == 0) { bbase[NB] = E; rowptr[n] = E; }
}

__global__ __launch_bounds__(256) void bpart_kernel(
        const int* __restrict__ dst, const int* __restrict__ rel, const int* __restrict__ src,
        int* __restrict__ bcursor, unsigned* __restrict__ bpacked, int E, int NB) {
    __shared__ int cntL[256];
    __shared__ int gofsL[256];
    int t = threadIdx.x;
    int e0 = blockIdx.x * 4096;
    cntL[t] = 0;
    __syncthreads();

    unsigned pv[16]; unsigned short li[16]; unsigned char bk[16];
#pragma unroll
    for (int j = 0; j < 16; j++) {
        int e = e0 + t + j * 256;
        bk[j] = 0xFF;
        if (e < E) {
            int d = dst[e];
            int b = d >> 9;
            bk[j] = (unsigned char)b;
            li[j] = (unsigned short)atomicAdd(&cntL[b], 1);
            pv[j] = ((unsigned)(d & 511) << 23) | ((unsigned)rel[e] << 19) | (unsigned)src[e];
        }
    }
    __syncthreads();
    for (int b = t; b < NB; b += 256) {
        int c = cntL[b];
        gofsL[b] = c ? atomicAdd(&bcursor[b], c) : 0;
    }
    __syncthreads();
#pragma unroll
    for (int j = 0; j < 16; j++)
        if (bk[j] != 0xFF) bpacked[gofsL[bk[j]] + li[j]] = pv[j];
}

#define BCAP 6400
__global__ __launch_bounds__(256) void bsort_kernel(
        const unsigned* __restrict__ bpacked, const int* __restrict__ bbase,
        int* __restrict__ rowptr, unsigned* __restrict__ packed, int n) {
    __shared__ unsigned ein[BCAP];
    __shared__ unsigned eout[BCAP];
    __shared__ int cnt[512];
    __shared__ int ofs[512];
    __shared__ int s2[256];
    int b = blockIdx.x, t = threadIdx.x;
    int g0 = bbase[b];
    int nb = bbase[b + 1] - g0;
    if (nb > BCAP) nb = BCAP;

    for (int i = t; i < nb; i += 256) ein[i] = bpacked[g0 + i];
    cnt[t] = 0; cnt[t + 256] = 0;
    __syncthreads();
    for (int i = t; i < nb; i += 256) atomicAdd(&cnt[ein[i] >> 23], 1);
    __syncthreads();
    int a = cnt[2 * t], c2 = cnt[2 * t + 1];
    s2[t] = a + c2;
    __syncthreads();
    for (int o = 1; o < 256; o <<= 1) {
        int u = (t >= o) ? s2[t - o] : 0;
        __syncthreads(); s2[t] += u; __syncthreads();
    }
    int excl = s2[t] - (a + c2);
    ofs[2 * t] = excl; ofs[2 * t + 1] = excl + a;
    __syncthreads();
    int d0 = b * 512;
    for (int j = t; j < 512; j += 256) {
        int gd = d0 + j;
        if (gd < n) rowptr[gd] = g0 + ofs[j];
    }
    cnt[t] = ofs[t]; cnt[t + 256] = ofs[t + 256];
    __syncthreads();
    for (int i = t; i < nb; i += 256) {
        unsigned v = ein[i];
        int pos = atomicAdd(&cnt[v >> 23], 1);
        eout[pos] = (((v >> 19) & 0xFu) << 24) | (v & 0x7FFFFu);
    }
    __syncthreads();
    for (int i = t; i < nb; i += 256) packed[g0 + i] = eout[i];
}

// ================= RGAT =================
// Vbpad[r][0][d]=bf16(Vsrc); row1=Vdst; rows 2..15 zero (memset)
__global__ void compute_v_kernel(const float* __restrict__ W,
                                 const float* __restrict__ a_src,
                                 const float* __restrict__ a_dst,
                                 unsigned short* __restrict__ Vbpad, int R) {
    int idx = blockIdx.x * blockDim.x + threadIdx.x;   // r*64+d
    if (idx >= R * 64) return;
    int r = idx >> 6, d = idx & 63;
    const float* Wr = W + idx * 64;
    const float* as = a_src + r * 64;
    const float* ad = a_dst + r * 64;
    float s = 0.f, t = 0.f;
    for (int e = 0; e < 64; e++) { float w = Wr[e]; s = fmaf(w, as[e], s); t = fmaf(w, ad[e], t); }
    Vbpad[(size_t)r * 1024 + d] = f2bf(s);
    Vbpad[(size_t)r * 1024 + 64 + d] = f2bf(t);
}

// slow-but-correct attention fallback (only used if hWb must be chunked)
__global__ void att_fallback_kernel(const void* __restrict__ h, int hBf16,
                                    const unsigned short* __restrict__ Vbpad,
                                    float* __restrict__ attS, float* __restrict__ attD,
                                    int n, int R) {
    int idx = blockIdx.x * blockDim.x + threadIdx.x;
    if (idx >= n * R) return;
    int node = idx / R, r = idx - node * R;
    float s = 0.f, dd = 0.f;
    for (int d = 0; d < 64; d++) {
        float hv = hBf16 ? bf2f(((const unsigned short*)h)[(size_t)node * 64 + d])
                         : ((const float*)h)[(size_t)node * 64 + d];
        s  = fmaf(hv, bf2f(Vbpad[(size_t)r * 1024 + d]), s);
        dd = fmaf(hv, bf2f(Vbpad[(size_t)r * 1024 + 64 + d]), dd);
    }
    attS[(size_t)node * R + r] = s;
    attD[(size_t)node * R + r] = dd;
}

// hW[rl,n,e] via bf16 MFMA + fused attention MFMA.
// A[m=lane&15][k=8*quad+j], B[n=lane&15][k=8*quad+j], D[row=4*quad+reg][col=lane&15]
#define BSTRIDE 72
__global__ __launch_bounds__(256) void hw_gemm_mfma_kernel(
        const void* __restrict__ hIn, int hBf16, const float* __restrict__ W,
        const unsigned short* __restrict__ Vbpad,
        unsigned short* __restrict__ hWb, float* __restrict__ attS, float* __restrict__ attD,
        int N, int R, int r0, int r1, int doAtt) {
    __shared__ unsigned short hb[64 * BSTRIDE];
    __shared__ unsigned short wt[64 * BSTRIDE];
    int t = threadIdx.x;
    int n0 = blockIdx.x * 64;

    if (hBf16) {
        const unsigned short* hg = (const unsigned short*)hIn;
#pragma unroll
        for (int i = 0; i < 2; i++) {
            int idx = t + i * 256;                 // 0..511 ushort8-chunks
            int row = idx >> 3, c8 = (idx & 7) * 8;
            int node = n0 + row;
            ushort4 v0 = {0, 0, 0, 0}, v1 = {0, 0, 0, 0};
            if (node < N) {
                v0 = *(const ushort4*)&hg[(size_t)node * 64 + c8];
                v1 = *(const ushort4*)&hg[(size_t)node * 64 + c8 + 4];
            }
            *(ushort4*)&hb[row * BSTRIDE + c8] = v0;
            *(ushort4*)&hb[row * BSTRIDE + c8 + 4] = v1;
        }
    } else {
        const float4* hg = (const float4*)hIn;
#pragma unroll
        for (int i = 0; i < 4; i++) {
            int idx = t + i * 256;
            int row = idx >> 4, c4 = idx & 15;
            int node = n0 + row;
            float4 v = (node < N) ? hg[(size_t)node * 16 + c4] : float4{0.f, 0.f, 0.f, 0.f};
            ushort4 b;
            b.x = f2bf(v.x); b.y = f2bf(v.y); b.z = f2bf(v.z); b.w = f2bf(v.w);
            *(ushort4*)&hb[row * BSTRIDE + c4 * 4] = b;
        }
    }
    __syncthreads();

    int w = t >> 6, lane = t & 63;
    int quad = lane >> 4, m = lane & 15;
    int arow = w * 16 + m;
    short8 a0 = *(const short8*)&hb[arow * BSTRIDE + quad * 8];
    short8 a1 = *(const short8*)&hb[arow * BSTRIDE + 32 + quad * 8];
    int nodeBase = n0 + w * 16 + quad * 4;

    for (int r = r0; r < r1; r++) {
        __syncthreads();
        {
            const float4* Wg = (const float4*)(W + (size_t)r * 4096);
#pragma unroll
            for (int i = 0; i < 4; i++) {
                int idx = t + i * 256;
                int k = idx >> 4, e4 = (idx & 15) * 4;
                float4 v = Wg[idx];
                wt[(e4 + 0) * BSTRIDE + k] = f2bf(v.x);
                wt[(e4 + 1) * BSTRIDE + k] = f2bf(v.y);
                wt[(e4 + 2) * BSTRIDE + k] = f2bf(v.z);
                wt[(e4 + 3) * BSTRIDE + k] = f2bf(v.w);
            }
        }
        __syncthreads();

        size_t outBase = ((size_t)(r - r0) * N + n0 + w * 16) * 64;
#pragma unroll
        for (int c = 0; c < 4; c++) {
            short8 b0 = *(const short8*)&wt[(c * 16 + m) * BSTRIDE + quad * 8];
            short8 b1 = *(const short8*)&wt[(c * 16 + m) * BSTRIDE + 32 + quad * 8];
            float4v acc = {0.f, 0.f, 0.f, 0.f};
            acc = __builtin_amdgcn_mfma_f32_16x16x32_bf16(a0, b0, acc, 0, 0, 0);
            acc = __builtin_amdgcn_mfma_f32_16x16x32_bf16(a1, b1, acc, 0, 0, 0);
#pragma unroll
            for (int reg = 0; reg < 4; reg++) {
                int node = nodeBase + reg;
                if (node < N)
                    hWb[outBase + (size_t)(quad * 4 + reg) * 64 + c * 16 + m] = f2bf(acc[reg]);
            }
        }
        if (doAtt) {
            const unsigned short* Vp = Vbpad + (size_t)r * 1024;
            short8 v0 = *(const short8*)&Vp[m * 64 + quad * 8];
            short8 v1 = *(const short8*)&Vp[m * 64 + 32 + quad * 8];
            float4v av = {0.f, 0.f, 0.f, 0.f};
            av = __builtin_amdgcn_mfma_f32_16x16x32_bf16(a0, v0, av, 0, 0, 0);
            av = __builtin_amdgcn_mfma_f32_16x16x32_bf16(a1, v1, av, 0, 0, 0);
            if (m < 2) {
                float* o = (m == 0) ? attS : attD;
#pragma unroll
                for (int reg = 0; reg < 4; reg++) {
                    int node = nodeBase + reg;
                    if (node < N) o[(size_t)node * R + r] = av[reg];
                }
            }
        }
    }
}

// ====== fused softmax + aggregation, grouped gather + pipelined chunk 0 ======
__global__ __launch_bounds__(256) void aggsoft_kernel(
        const int* __restrict__ rowptr, const unsigned* __restrict__ packed,
        const float* __restrict__ attS, const float* __restrict__ attD,
        const unsigned short* __restrict__ hWb, float* __restrict__ agg,
        unsigned short* __restrict__ hbOut,
        int n, int N, int R, int r0, int r1, int last) {
    int g = blockIdx.x * blockDim.x + threadIdx.x;
    int wv = g >> 6, lane = g & 63;
    if (wv >= n) return;
    int start = rowptr[wv], end = rowptr[wv + 1];
    int deg = end - start;
    int egrp = lane >> 3, dgrp = lane & 7;

    float acc8[8] = {0.f, 0.f, 0.f, 0.f, 0.f, 0.f, 0.f, 0.f};
    if (r0 != 0) {
#pragma unroll
        for (int j = 0; j < 8; j += 4) {
            float4 v = *(const float4*)&agg[(size_t)wv * 64 + dgrp * 8 + j];
            acc8[j] = v.x; acc8[j + 1] = v.y; acc8[j + 2] = v.z; acc8[j + 3] = v.w;
        }
    }

    if (deg > 0 && deg <= 64) {
        int i = start + lane;
        bool act = i < end;
        unsigned p = act ? packed[i] : 0u;
        int r = p >> 24; unsigned s = p & 0xFFFFFFu;

        unsigned pp0 = (unsigned)__shfl((int)p, egrp);
        int rr0 = (int)(pp0 >> 24);
        bool g0 = (egrp < deg) && rr0 >= r0 && rr0 < r1;
        ushort8v v0 = {};
        if (g0) {
            unsigned row = (unsigned)((rr0 - r0) * N) + (pp0 & 0xFFFFFFu);
            v0 = *(const ushort8v*)&hWb[((size_t)row << 6) + dgrp * 8];
        }

        float sc = -INFINITY;
        if (act) {
            sc = attS[(size_t)s * R + r] + attD[(size_t)wv * R + r];
            sc = sc > 0.f ? sc : NEG_SLOPE * sc;
        }
        float m = sc, sum;
        if (deg <= 8) {
            for (int o = 4; o; o >>= 1) m = fmaxf(m, __shfl_xor(m, o));
            float ex = act ? __expf(sc - m) : 0.f;
            sum = ex;
            for (int o = 4; o; o >>= 1) sum += __shfl_xor(sum, o);
            sc = ex;
        } else {
            for (int o = 32; o; o >>= 1) m = fmaxf(m, __shfl_xor(m, o));
            float ex = act ? __expf(sc - m) : 0.f;
            sum = ex;
            for (int o = 32; o; o >>= 1) sum += __shfl_xor(sum, o);
            sc = ex;
        }
        float a = sc * __builtin_amdgcn_rcpf(sum + 1e-9f);
        float ag = (act && r >= r0 && r < r1) ? a : 0.f;

        {
            float aa = __shfl(ag, egrp);
            if (g0 && aa != 0.f) {
#pragma unroll
                for (int j = 0; j < 8; j++) acc8[j] = fmaf(aa, bf2f(v0[j]), acc8[j]);
            }
        }
        int nchunk = (deg + 7) >> 3;
        for (int c = 1; c < nchunk; c++) {
            int el = c * 8 + egrp;
            float aa = __shfl(ag, el);
            unsigned pp = (unsigned)__shfl((int)p, el);
            if (aa != 0.f) {
                unsigned row = (unsigned)(((pp >> 24) - r0) * (unsigned)N) + (pp & 0xFFFFFFu);
                ushort8v v = *(const ushort8v*)&hWb[((size_t)row << 6) + dgrp * 8];
#pragma unroll
                for (int j = 0; j < 8; j++) acc8[j] = fmaf(aa, bf2f(v[j]), acc8[j]);
            }
        }
#pragma unroll
        for (int msk = 8; msk <= 32; msk <<= 1)
#pragma unroll
            for (int j = 0; j < 8; j++) acc8[j] += __shfl_xor(acc8[j], msk);
    } else if (deg > 64) {
        float m = -INFINITY;
        for (int base = start; base < end; base += 64) {
            int i = base + lane;
            if (i < end) {
                unsigned p = packed[i];
                int r = p >> 24; unsigned s = p & 0xFFFFFFu;
                float sc = attS[(size_t)s * R + r] + attD[(size_t)wv * R + r];
                sc = sc > 0.f ? sc : NEG_SLOPE * sc;
                m = fmaxf(m, sc);
            }
        }
        for (int o = 32; o; o >>= 1) m = fmaxf(m, __shfl_xor(m, o));
        float sum = 0.f;
        for (int base = start; base < end; base += 64) {
            int i = base + lane;
            if (i < end) {
                unsigned p = packed[i];
                int r = p >> 24; unsigned s = p & 0xFFFFFFu;
                float sc = attS[(size_t)s * R + r] + attD[(size_t)wv * R + r];
                sc = sc > 0.f ? sc : NEG_SLOPE * sc;
                sum += __expf(sc - m);
            }
        }
        for (int o = 32; o; o >>= 1) sum += __shfl_xor(sum, o);
        float inv = __builtin_amdgcn_rcpf(sum + 1e-9f);
        int nchunk = (deg + 7) >> 3;
        for (int c = 0; c < nchunk; c++) {
            int el = c * 8 + egrp;
            if (el < deg) {
                unsigned p = packed[start + el];
                int r = p >> 24; unsigned s = p & 0xFFFFFFu;
                if (r >= r0 && r < r1) {
                    float sc = attS[(size_t)s * R + r] + attD[(size_t)wv * R + r];
                    sc = sc > 0.f ? sc : NEG_SLOPE * sc;
                    float aa = __expf(sc - m) * inv;
                    unsigned row = (unsigned)((r - r0) * N) + s;
                    ushort8v v = *(const ushort8v*)&hWb[((size_t)row << 6) + dgrp * 8];
#pragma unroll
                    for (int j = 0; j < 8; j++) acc8[j] = fmaf(aa, bf2f(v[j]), acc8[j]);
                }
            }
        }
#pragma unroll
        for (int msk = 8; msk <= 32; msk <<= 1)
#pragma unroll
            for (int j = 0; j < 8; j++) acc8[j] += __shfl_xor(acc8[j], msk);
    }

    if (last) {
#pragma unroll
        for (int j = 0; j < 8; j++)
            acc8[j] = acc8[j] > 0.f ? acc8[j] : (__expf(acc8[j]) - 1.f);
        if (egrp == 0) {
            if (hbOut) {
                ushort4 o0, o1;
                o0.x = f2bf(acc8[0]); o0.y = f2bf(acc8[1]); o0.z = f2bf(acc8[2]); o0.w = f2bf(acc8[3]);
                o1.x = f2bf(acc8[4]); o1.y = f2bf(acc8[5]); o1.z = f2bf(acc8[6]); o1.w = f2bf(acc8[7]);
                *(ushort4*)&hbOut[(size_t)wv * 64 + dgrp * 8] = o0;
                *(ushort4*)&hbOut[(size_t)wv * 64 + dgrp * 8 + 4] = o1;
            } else {
                float4 v0 = {acc8[0], acc8[1], acc8[2], acc8[3]};
                float4 v1 = {acc8[4], acc8[5], acc8[6], acc8[7]};
                *(float4*)&agg[(size_t)wv * 64 + dgrp * 8] = v0;
                *(float4*)&agg[(size_t)wv * 64 + dgrp * 8 + 4] = v1;
            }
        }
    } else if (egrp == 0) {
        float4 v0 = {acc8[0], acc8[1], acc8[2], acc8[3]};
        float4 v1 = {acc8[4], acc8[5], acc8[6], acc8[7]};
        *(float4*)&agg[(size_t)wv * 64 + dgrp * 8] = v0;
        *(float4*)&agg[(size_t)wv * 64 + dgrp * 8 + 4] = v1;
    }
}

// ================= pooling / readout =================
__global__ void seg_sum64_kernel(const float* __restrict__ h, const int* __restrict__ seg,
                                 float* __restrict__ out, int N) {
    int i = blockIdx.x * blockDim.x + threadIdx.x;
    if (i >= N * 64) return;
    int n = i >> 6, d = i & 63;
    atomAddF(&out[seg[n] * 64 + d], h[i]);
}

__global__ void readout_kernel(const float* __restrict__ molr, const float* __restrict__ mol,
                               const int* __restrict__ mol2rxn, float* __restrict__ feat, int M) {
    int i = blockIdx.x * blockDim.x + threadIdx.x;
    if (i >= M * 64) return;
    int m = i >> 6, d = i & 63;
    int b = mol2rxn[m];
    atomAddF(&feat[b * 128 + d], molr[i]);
    atomAddF(&feat[b * 128 + 64 + d], mol[i]);
}

// ================= MLP head: LDS-tiled GEMM =================
#define APAD 36
__global__ __launch_bounds__(256) void fc_gemm_kernel(
        const float* __restrict__ A, const float* __restrict__ B,
        const float* __restrict__ bias, const float* __restrict__ prelu,
        float* __restrict__ C, int M, int N, int K, int mode) {
    __shared__ float Al[64 * APAD];
    __shared__ float Bl[32 * 64];
    int t = threadIdx.x;
    int n0 = blockIdx.x * 64, m0 = blockIdx.y * 64;
    int e4 = (t & 15) * 4;
    int n4 = (t >> 4) * 4;
    float acc[4][4] = {};

    for (int k0 = 0; k0 < K; k0 += 32) {
        {
            const float4* Ag = (const float4*)A;
#pragma unroll
            for (int i = 0; i < 2; i++) {
                int idx = t + i * 256;
                int row = idx >> 3, c4 = idx & 7;
                float4 v = Ag[(size_t)(m0 + row) * (K >> 2) + (k0 >> 2) + c4];
                float* p = &Al[row * APAD + c4 * 4];
                p[0] = v.x; p[1] = v.y; p[2] = v.z; p[3] = v.w;
            }
        }
        {
#pragma unroll
            for (int i = 0; i < 2; i++) {
                int idx = t + i * 256;
                int kk = idx >> 4, c4 = (idx & 15) * 4;
                int col = n0 + c4;
                float4 v;
                const float* Brow = B + (size_t)(k0 + kk) * N;
                if (col + 3 < N) v = *(const float4*)&Brow[col];
                else {
                    v.x = (col + 0 < N) ? Brow[col + 0] : 0.f;
                    v.y = (col + 1 < N) ? Brow[col + 1] : 0.f;
                    v.z = (col + 2 < N) ? Brow[col + 2] : 0.f;
                    v.w = 0.f;
                }
                *(float4*)&Bl[kk * 64 + c4] = v;
            }
        }
        __syncthreads();
        for (int d = 0; d < 32; d += 4) {
            float4 wv[4], hv[4];
#pragma unroll
            for (int dd = 0; dd < 4; dd++) wv[dd] = *(const float4*)&Bl[(d + dd) * 64 + e4];
#pragma unroll
            for (int i = 0; i < 4; i++) hv[i] = *(const float4*)&Al[(n4 + i) * APAD + d];
#pragma unroll
            for (int i = 0; i < 4; i++) {
                const float hvv[4] = {hv[i].x, hv[i].y, hv[i].z, hv[i].w};
#pragma unroll
                for (int dd = 0; dd < 4; dd++) {
                    const float* wp = (const float*)&wv[dd];
#pragma unroll
                    for (int j = 0; j < 4; j++) acc[i][j] = fmaf(hvv[dd], wp[j], acc[i][j]);
                }
            }
        }
        __syncthreads();
    }

    float p = mode ? *prelu : 0.f;
#pragma unroll
    for (int i = 0; i < 4; i++) {
        int row = m0 + n4 + i;
#pragma unroll
        for (int j = 0; j < 4; j++) {
            int col = n0 + e4 + j;
            if (col < N) {
                float v = acc[i][j] + bias[col];
                if (mode) v = v > 0.f ? v : p * v;
                C[(size_t)row * N + col] = v;
            }
        }
    }
}

// ================= launch =================
extern "C" void kernel_launch(void* const* d_in, const int* in_sizes, int n_in,
                              void* d_out, int out_size, void* d_ws, size_t ws_size,
                              hipStream_t stream) {
    const float* node_feats = (const float*)d_in[0];
    const int*   edge_src   = (const int*)d_in[1];
    const int*   edge_dst   = (const int*)d_in[2];
    const int*   edge_rel   = (const int*)d_in[3];
    const int*   node2mol   = (const int*)d_in[4];
    const int*   rxn_src    = (const int*)d_in[5];
    const int*   rxn_dst    = (const int*)d_in[6];
    const int*   rxn_rel    = (const int*)d_in[7];
    const int*   mol2rxn    = (const int*)d_in[8];
    const float* W1     = (const float*)d_in[9];
    const float* a_src1 = (const float*)d_in[10];
    const float* a_dst1 = (const float*)d_in[11];
    const float* W2     = (const float*)d_in[12];
    const float* a_src2 = (const float*)d_in[13];
    const float* a_dst2 = (const float*)d_in[14];
    const float* Wr     = (const float*)d_in[15];
    const float* a_srcr = (const float*)d_in[16];
    const float* a_dstr = (const float*)d_in[17];
    const float* w_fc1  = (const float*)d_in[18];
    const float* b_fc1  = (const float*)d_in[19];
    const float* prelu1 = (const float*)d_in[20];
    const float* w_fc2  = (const float*)d_in[21];
    const float* b_fc2  = (const float*)d_in[22];

    const int N = 100000, E = 800000, M = 5000, ER = 40000;

    float* ws = (float*)d_ws;
    unsigned short* hb1 = (unsigned short*)ws;        // 6.4M ush (layer-1 h, bf16)
    float* h2     = (float*)(hb1 + 6400000);          // 6.4M f (layer-2 out; also L1 carry scratch)
    float* attS   = h2 + 6400000;                     // 800K
    float* attD   = attS + 800000;                    // 800K
    float* mol    = attD + 800000;                    // 320K
    float* molr   = mol + 320000;                     // 320K
    float* feat   = molr + 320000;                    // 131072
    float* hm     = feat + 131072;                    // 524288
    unsigned short* Vbpad = (unsigned short*)(hm + 524288);  // 8*16*64 = 8192 ush
    int* rowptr   = (int*)(Vbpad + 8192);             // 100008
    int* bcnt     = rowptr + 100008;                  // 256
    int* bbase    = bcnt + 256;                       // 260
    int* bcursor  = bbase + 260;                      // 256
    unsigned* bpacked = (unsigned*)(bcursor + 256);   // 800000
    unsigned* packed  = bpacked + 800000;             // 800000
    unsigned short* hWb = (unsigned short*)(packed + 800000); // bf16 hW (chunked)

    size_t usedBytes = (size_t)((char*)hWb - (char*)d_ws);
    size_t availUshorts = (ws_size > usedBytes) ? (ws_size - usedBytes) / 2 : 0;

    auto buildCSR = [&](const int* dstArr, const int* srcArr, const int* relArr, int n, int e) {
        int NB = (n + 511) / 512;
        hipMemsetAsync(bcnt, 0, (size_t)NB * sizeof(int), stream);
        bhist_kernel<<<dim3(256), 256, 0, stream>>>(dstArr, bcnt, e);
        bscan_kernel<<<dim3(1), 256, 0, stream>>>(bcnt, bbase, bcursor, NB, rowptr, n, e);
        bpart_kernel<<<dim3((e + 4095) / 4096), 256, 0, stream>>>(dstArr, relArr, srcArr, bcursor, bpacked, e, NB);
        bsort_kernel<<<dim3(NB), 256, 0, stream>>>(bpacked, bbase, rowptr, packed, n);
    };

    auto rgat = [&](const void* hin, int hBf16, int n,
                    const float* W, const float* as, const float* ad,
                    float* agg, unsigned short* hbOut, int R) {
        hipMemsetAsync(Vbpad, 0, (size_t)R * 1024 * 2, stream);
        compute_v_kernel<<<dim3((R * 64 + 63) / 64), 64, 0, stream>>>(W, as, ad, Vbpad, R);

        size_t perRel = (size_t)n * 64;   // ushorts per relation
        int chunk = (int)(availUshorts / perRel);
        if (chunk < 1) chunk = 1;
        if (chunk > R) chunk = R;
        int fused = (chunk == R) ? 1 : 0;
        if (!fused)
            att_fallback_kernel<<<dim3((n * R + 255) / 256), 256, 0, stream>>>(
                hin, hBf16, Vbpad, attS, attD, n, R);
        for (int r0 = 0; r0 < R; r0 += chunk) {
            int r1 = r0 + chunk; if (r1 > R) r1 = R;
            hw_gemm_mfma_kernel<<<dim3((n + 63) / 64), 256, 0, stream>>>(
                hin, hBf16, W, Vbpad, hWb, attS, attD, n, R, r0, r1, fused);
            aggsoft_kernel<<<dim3(((size_t)n * 64 + 255) / 256), 256, 0, stream>>>(
                rowptr, packed, attS, attD, hWb, agg, hbOut, n, n, R, r0, r1, r1 == R ? 1 : 0);
        }
    };

    // ---- atom graph ----
    buildCSR(edge_dst, edge_src, edge_rel, N, E);
    // layer 1: fp32 input -> bf16 output (h2 used as fp32 carry scratch if chunked)
    rgat(node_feats, 0, N, W1, a_src1, a_dst1, h2, hb1, 8);
    // layer 2: bf16 input -> fp32 output h2
    rgat(hb1, 1, N, W2, a_src2, a_dst2, h2, nullptr, 8);

    // ---- molecule pooling ----
    hipMemsetAsync(mol, 0, (size_t)M * 64 * sizeof(float), stream);
    seg_sum64_kernel<<<dim3(((size_t)N * 64 + 255) / 256), 256, 0, stream>>>(h2, node2mol, mol, N);

    // ---- reaction-graph RGAT ----
    buildCSR(rxn_dst, rxn_src, rxn_rel, M, ER);
    rgat(mol, 0, M, Wr, a_srcr, a_dstr, molr, nullptr, 4);

    // ---- reaction readout ----
    hipMemsetAsync(feat, 0, (size_t)1024 * 128 * sizeof(float), stream);
    readout_kernel<<<dim3(((size_t)M * 64 + 255) / 256), 256, 0, stream>>>(molr, mol, mol2rxn, feat, M);

    // ---- MLP head: tiled GEMMs ----
    fc_gemm_kernel<<<dim3(8, 16), 256, 0, stream>>>(feat, w_fc1, b_fc1, prelu1, hm, 1024, 512, 128, 1);
    fc_gemm_kernel<<<dim3(11, 16), 256, 0, stream>>>(hm, w_fc2, b_fc2, nullptr, (float*)d_out, 1024, 703, 512, 0);
}

// Round 15
// 503.045 us; speedup vs baseline: 1.0132x; 1.0132x over previous
//
#include <hip/hip_runtime.h>
#include <math.h>

#define NEG_SLOPE 0.2f

typedef __attribute__((ext_vector_type(8))) short short8;
typedef __attribute__((ext_vector_type(8))) unsigned short ushort8v;
typedef __attribute__((ext_vector_type(4))) float float4v;

__device__ __forceinline__ void atomAddF(float* p, float v) {
    unsafeAtomicAdd(p, v);   // HW global_atomic_add_f32 on gfx950
}
__device__ __forceinline__ unsigned short f2bf(float f) {
    unsigned u = __float_as_uint(f);
    unsigned r = (u + 0x7FFFu + ((u >> 16) & 1u)) >> 16;   // RNE
    return (unsigned short)r;
}
__device__ __forceinline__ float bf2f(unsigned short b) {
    return __uint_as_float((unsigned)b << 16);
}

// ================= CSR build: two-pass LDS-binned sort =================
__global__ void bhist_kernel(const int* __restrict__ dst, int* __restrict__ bcnt, int E) {
    __shared__ int h[256];
    int t = threadIdx.x;
    h[t] = 0;
    __syncthreads();
    for (int e = blockIdx.x * blockDim.x + t; e < E; e += gridDim.x * blockDim.x)
        atomicAdd(&h[dst[e] >> 9], 1);
    __syncthreads();
    if (h[t]) atomicAdd(&bcnt[t], h[t]);
}

__global__ void bscan_kernel(const int* __restrict__ bcnt, int* __restrict__ bbase,
                             int* __restrict__ bcursor, int NB, int* __restrict__ rowptr,
                             int n, int E) {
    __shared__ int s[256];
    int t = threadIdx.x;
    int v = (t < NB) ? bcnt[t] : 0;
    s[t] = v; __syncthreads();
    for (int o = 1; o < 256; o <<= 1) {
        int u = (t >= o) ? s[t - o] : 0;
        __syncthreads(); s[t] += u; __syncthreads();
    }
    int excl = s[t] - v;
    if (t < NB) { bbase[t] = excl; bcursor[t] = excl; }
    if (t == 0) { bbase[NB] = E; rowptr[n] = E; }
}

__global__ __launch_bounds__(256) void bpart_kernel(
        const int* __restrict__ dst, const int* __restrict__ rel, const int* __restrict__ src,
        int* __restrict__ bcursor, unsigned* __restrict__ bpacked, int E, int NB) {
    __shared__ int cntL[256];
    __shared__ int gofsL[256];
    int t = threadIdx.x;
    int e0 = blockIdx.x * 4096;
    cntL[t] = 0;
    __syncthreads();

    unsigned pv[16]; unsigned short li[16]; unsigned char bk[16];
#pragma unroll
    for (int j = 0; j < 16; j++) {
        int e = e0 + t + j * 256;
        bk[j] = 0xFF;
        if (e < E) {
            int d = dst[e];
            int b = d >> 9;
            bk[j] = (unsigned char)b;
            li[j] = (unsigned short)atomicAdd(&cntL[b], 1);
            pv[j] = ((unsigned)(d & 511) << 23) | ((unsigned)rel[e] << 19) | (unsigned)src[e];
        }
    }
    __syncthreads();
    for (int b = t; b < NB; b += 256) {
        int c = cntL[b];
        gofsL[b] = c ? atomicAdd(&bcursor[b], c) : 0;
    }
    __syncthreads();
#pragma unroll
    for (int j = 0; j < 16; j++)
        if (bk[j] != 0xFF) bpacked[gofsL[bk[j]] + li[j]] = pv[j];
}

#define BCAP 6400
__global__ __launch_bounds__(256) void bsort_kernel(
        const unsigned* __restrict__ bpacked, const int* __restrict__ bbase,
        int* __restrict__ rowptr, unsigned* __restrict__ packed, int n) {
    __shared__ unsigned ein[BCAP];
    __shared__ unsigned eout[BCAP];
    __shared__ int cnt[512];
    __shared__ int ofs[512];
    __shared__ int s2[256];
    int b = blockIdx.x, t = threadIdx.x;
    int g0 = bbase[b];
    int nb = bbase[b + 1] - g0;
    if (nb > BCAP) nb = BCAP;

    for (int i = t; i < nb; i += 256) ein[i] = bpacked[g0 + i];
    cnt[t] = 0; cnt[t + 256] = 0;
    __syncthreads();
    for (int i = t; i < nb; i += 256) atomicAdd(&cnt[ein[i] >> 23], 1);
    __syncthreads();
    int a = cnt[2 * t], c2 = cnt[2 * t + 1];
    s2[t] = a + c2;
    __syncthreads();
    for (int o = 1; o < 256; o <<= 1) {
        int u = (t >= o) ? s2[t - o] : 0;
        __syncthreads(); s2[t] += u; __syncthreads();
    }
    int excl = s2[t] - (a + c2);
    ofs[2 * t] = excl; ofs[2 * t + 1] = excl + a;
    __syncthreads();
    int d0 = b * 512;
    for (int j = t; j < 512; j += 256) {
        int gd = d0 + j;
        if (gd < n) rowptr[gd] = g0 + ofs[j];
    }
    cnt[t] = ofs[t]; cnt[t + 256] = ofs[t + 256];
    __syncthreads();
    for (int i = t; i < nb; i += 256) {
        unsigned v = ein[i];
        int pos = atomicAdd(&cnt[v >> 23], 1);
        eout[pos] = (((v >> 19) & 0xFu) << 24) | (v & 0x7FFFFu);
    }
    __syncthreads();
    for (int i = t; i < nb; i += 256) packed[g0 + i] = eout[i];
}

// ================= RGAT =================
// Vbpad[r][0][d]=bf16(Vsrc); row1=Vdst; rows 2..15 zero (memset)
__global__ void compute_v_kernel(const float* __restrict__ W,
                                 const float* __restrict__ a_src,
                                 const float* __restrict__ a_dst,
                                 unsigned short* __restrict__ Vbpad, int R) {
    int idx = blockIdx.x * blockDim.x + threadIdx.x;   // r*64+d
    if (idx >= R * 64) return;
    int r = idx >> 6, d = idx & 63;
    const float* Wr = W + idx * 64;
    const float* as = a_src + r * 64;
    const float* ad = a_dst + r * 64;
    float s = 0.f, t = 0.f;
    for (int e = 0; e < 64; e++) { float w = Wr[e]; s = fmaf(w, as[e], s); t = fmaf(w, ad[e], t); }
    Vbpad[(size_t)r * 1024 + d] = f2bf(s);
    Vbpad[(size_t)r * 1024 + 64 + d] = f2bf(t);
}

// slow-but-correct attention fallback (only used if hWb must be chunked)
__global__ void att_fallback_kernel(const void* __restrict__ h, int hBf16,
                                    const unsigned short* __restrict__ Vbpad,
                                    float* __restrict__ attS, float* __restrict__ attD,
                                    int n, int R) {
    int idx = blockIdx.x * blockDim.x + threadIdx.x;
    if (idx >= n * R) return;
    int node = idx / R, r = idx - node * R;
    float s = 0.f, dd = 0.f;
    for (int d = 0; d < 64; d++) {
        float hv = hBf16 ? bf2f(((const unsigned short*)h)[(size_t)node * 64 + d])
                         : ((const float*)h)[(size_t)node * 64 + d];
        s  = fmaf(hv, bf2f(Vbpad[(size_t)r * 1024 + d]), s);
        dd = fmaf(hv, bf2f(Vbpad[(size_t)r * 1024 + 64 + d]), dd);
    }
    attS[(size_t)node * R + r] = s;
    attD[(size_t)node * R + r] = dd;
}

// hW[rl,n,e] via bf16 MFMA + fused attention MFMA.
// A[m=lane&15][k=8*quad+j], B[n=lane&15][k=8*quad+j], D[row=4*quad+reg][col=lane&15]
// BSTRIDE=68 ushorts = 136 B row stride: 8 B (2-bank) shift per row -> 16 fragment
// rows cover 16 distinct bank pairs, only 2-way lane aliasing (free per m136).
// (72 = 144 B = 4-bank shift gave 8-way conflicts: 1.29e7 SQ_LDS_BANK_CONFLICT.)
#define BSTRIDE 68
__global__ __launch_bounds__(256) void hw_gemm_mfma_kernel(
        const void* __restrict__ hIn, int hBf16, const float* __restrict__ W,
        const unsigned short* __restrict__ Vbpad,
        unsigned short* __restrict__ hWb, float* __restrict__ attS, float* __restrict__ attD,
        int N, int R, int r0, int r1, int doAtt) {
    __shared__ unsigned short hb[64 * BSTRIDE];
    __shared__ unsigned short wt[64 * BSTRIDE];
    int t = threadIdx.x;
    int n0 = blockIdx.x * 64;

    if (hBf16) {
        const unsigned short* hg = (const unsigned short*)hIn;
#pragma unroll
        for (int i = 0; i < 2; i++) {
            int idx = t + i * 256;                 // 0..511 ushort8-chunks
            int row = idx >> 3, c8 = (idx & 7) * 8;
            int node = n0 + row;
            ushort4 v0 = {0, 0, 0, 0}, v1 = {0, 0, 0, 0};
            if (node < N) {
                v0 = *(const ushort4*)&hg[(size_t)node * 64 + c8];
                v1 = *(const ushort4*)&hg[(size_t)node * 64 + c8 + 4];
            }
            *(ushort4*)&hb[row * BSTRIDE + c8] = v0;
            *(ushort4*)&hb[row * BSTRIDE + c8 + 4] = v1;
        }
    } else {
        const float4* hg = (const float4*)hIn;
#pragma unroll
        for (int i = 0; i < 4; i++) {
            int idx = t + i * 256;
            int row = idx >> 4, c4 = idx & 15;
            int node = n0 + row;
            float4 v = (node < N) ? hg[(size_t)node * 16 + c4] : float4{0.f, 0.f, 0.f, 0.f};
            ushort4 b;
            b.x = f2bf(v.x); b.y = f2bf(v.y); b.z = f2bf(v.z); b.w = f2bf(v.w);
            *(ushort4*)&hb[row * BSTRIDE + c4 * 4] = b;
        }
    }
    __syncthreads();

    int w = t >> 6, lane = t & 63;
    int quad = lane >> 4, m = lane & 15;
    int arow = w * 16 + m;
    short8 a0 = *(const short8*)&hb[arow * BSTRIDE + quad * 8];
    short8 a1 = *(const short8*)&hb[arow * BSTRIDE + 32 + quad * 8];
    int nodeBase = n0 + w * 16 + quad * 4;

    for (int r = r0; r < r1; r++) {
        __syncthreads();
        {
            const float4* Wg = (const float4*)(W + (size_t)r * 4096);
#pragma unroll
            for (int i = 0; i < 4; i++) {
                int idx = t + i * 256;
                int k = idx >> 4, e4 = (idx & 15) * 4;
                float4 v = Wg[idx];
                wt[(e4 + 0) * BSTRIDE + k] = f2bf(v.x);
                wt[(e4 + 1) * BSTRIDE + k] = f2bf(v.y);
                wt[(e4 + 2) * BSTRIDE + k] = f2bf(v.z);
                wt[(e4 + 3) * BSTRIDE + k] = f2bf(v.w);
            }
        }
        __syncthreads();

        size_t outBase = ((size_t)(r - r0) * N + n0 + w * 16) * 64;
#pragma unroll
        for (int c = 0; c < 4; c++) {
            short8 b0 = *(const short8*)&wt[(c * 16 + m) * BSTRIDE + quad * 8];
            short8 b1 = *(const short8*)&wt[(c * 16 + m) * BSTRIDE + 32 + quad * 8];
            float4v acc = {0.f, 0.f, 0.f, 0.f};
            acc = __builtin_amdgcn_mfma_f32_16x16x32_bf16(a0, b0, acc, 0, 0, 0);
            acc = __builtin_amdgcn_mfma_f32_16x16x32_bf16(a1, b1, acc, 0, 0, 0);
#pragma unroll
            for (int reg = 0; reg < 4; reg++) {
                int node = nodeBase + reg;
                if (node < N)
                    hWb[outBase + (size_t)(quad * 4 + reg) * 64 + c * 16 + m] = f2bf(acc[reg]);
            }
        }
        if (doAtt) {
            const unsigned short* Vp = Vbpad + (size_t)r * 1024;
            short8 v0 = *(const short8*)&Vp[m * 64 + quad * 8];
            short8 v1 = *(const short8*)&Vp[m * 64 + 32 + quad * 8];
            float4v av = {0.f, 0.f, 0.f, 0.f};
            av = __builtin_amdgcn_mfma_f32_16x16x32_bf16(a0, v0, av, 0, 0, 0);
            av = __builtin_amdgcn_mfma_f32_16x16x32_bf16(a1, v1, av, 0, 0, 0);
            if (m < 2) {
                float* o = (m == 0) ? attS : attD;
#pragma unroll
                for (int reg = 0; reg < 4; reg++) {
                    int node = nodeBase + reg;
                    if (node < N) o[(size_t)node * R + r] = av[reg];
                }
            }
        }
    }
}

// ====== fused softmax + aggregation, grouped gather + pipelined chunk 0 ======
__global__ __launch_bounds__(256) void aggsoft_kernel(
        const int* __restrict__ rowptr, const unsigned* __restrict__ packed,
        const float* __restrict__ attS, const float* __restrict__ attD,
        const unsigned short* __restrict__ hWb, float* __restrict__ agg,
        unsigned short* __restrict__ hbOut,
        int n, int N, int R, int r0, int r1, int last) {
    int g = blockIdx.x * blockDim.x + threadIdx.x;
    int wv = g >> 6, lane = g & 63;
    if (wv >= n) return;
    int start = rowptr[wv], end = rowptr[wv + 1];
    int deg = end - start;
    int egrp = lane >> 3, dgrp = lane & 7;

    float acc8[8] = {0.f, 0.f, 0.f, 0.f, 0.f, 0.f, 0.f, 0.f};
    if (r0 != 0) {
#pragma unroll
        for (int j = 0; j < 8; j += 4) {
            float4 v = *(const float4*)&agg[(size_t)wv * 64 + dgrp * 8 + j];
            acc8[j] = v.x; acc8[j + 1] = v.y; acc8[j + 2] = v.z; acc8[j + 3] = v.w;
        }
    }

    if (deg > 0 && deg <= 64) {
        int i = start + lane;
        bool act = i < end;
        unsigned p = act ? packed[i] : 0u;
        int r = p >> 24; unsigned s = p & 0xFFFFFFu;

        unsigned pp0 = (unsigned)__shfl((int)p, egrp);
        int rr0 = (int)(pp0 >> 24);
        bool g0 = (egrp < deg) && rr0 >= r0 && rr0 < r1;
        ushort8v v0 = {};
        if (g0) {
            unsigned row = (unsigned)((rr0 - r0) * N) + (pp0 & 0xFFFFFFu);
            v0 = *(const ushort8v*)&hWb[((size_t)row << 6) + dgrp * 8];
        }

        float sc = -INFINITY;
        if (act) {
            sc = attS[(size_t)s * R + r] + attD[(size_t)wv * R + r];
            sc = sc > 0.f ? sc : NEG_SLOPE * sc;
        }
        float m = sc, sum;
        if (deg <= 8) {
            for (int o = 4; o; o >>= 1) m = fmaxf(m, __shfl_xor(m, o));
            float ex = act ? __expf(sc - m) : 0.f;
            sum = ex;
            for (int o = 4; o; o >>= 1) sum += __shfl_xor(sum, o);
            sc = ex;
        } else {
            for (int o = 32; o; o >>= 1) m = fmaxf(m, __shfl_xor(m, o));
            float ex = act ? __expf(sc - m) : 0.f;
            sum = ex;
            for (int o = 32; o; o >>= 1) sum += __shfl_xor(sum, o);
            sc = ex;
        }
        float a = sc * __builtin_amdgcn_rcpf(sum + 1e-9f);
        float ag = (act && r >= r0 && r < r1) ? a : 0.f;

        {
            float aa = __shfl(ag, egrp);
            if (g0 && aa != 0.f) {
#pragma unroll
                for (int j = 0; j < 8; j++) acc8[j] = fmaf(aa, bf2f(v0[j]), acc8[j]);
            }
        }
        int nchunk = (deg + 7) >> 3;
        for (int c = 1; c < nchunk; c++) {
            int el = c * 8 + egrp;
            float aa = __shfl(ag, el);
            unsigned pp = (unsigned)__shfl((int)p, el);
            if (aa != 0.f) {
                unsigned row = (unsigned)(((pp >> 24) - r0) * (unsigned)N) + (pp & 0xFFFFFFu);
                ushort8v v = *(const ushort8v*)&hWb[((size_t)row << 6) + dgrp * 8];
#pragma unroll
                for (int j = 0; j < 8; j++) acc8[j] = fmaf(aa, bf2f(v[j]), acc8[j]);
            }
        }
#pragma unroll
        for (int msk = 8; msk <= 32; msk <<= 1)
#pragma unroll
            for (int j = 0; j < 8; j++) acc8[j] += __shfl_xor(acc8[j], msk);
    } else if (deg > 64) {
        float m = -INFINITY;
        for (int base = start; base < end; base += 64) {
            int i = base + lane;
            if (i < end) {
                unsigned p = packed[i];
                int r = p >> 24; unsigned s = p & 0xFFFFFFu;
                float sc = attS[(size_t)s * R + r] + attD[(size_t)wv * R + r];
                sc = sc > 0.f ? sc : NEG_SLOPE * sc;
                m = fmaxf(m, sc);
            }
        }
        for (int o = 32; o; o >>= 1) m = fmaxf(m, __shfl_xor(m, o));
        float sum = 0.f;
        for (int base = start; base < end; base += 64) {
            int i = base + lane;
            if (i < end) {
                unsigned p = packed[i];
                int r = p >> 24; unsigned s = p & 0xFFFFFFu;
                float sc = attS[(size_t)s * R + r] + attD[(size_t)wv * R + r];
                sc = sc > 0.f ? sc : NEG_SLOPE * sc;
                sum += __expf(sc - m);
            }
        }
        for (int o = 32; o; o >>= 1) sum += __shfl_xor(sum, o);
        float inv = __builtin_amdgcn_rcpf(sum + 1e-9f);
        int nchunk = (deg + 7) >> 3;
        for (int c = 0; c < nchunk; c++) {
            int el = c * 8 + egrp;
            if (el < deg) {
                unsigned p = packed[start + el];
                int r = p >> 24; unsigned s = p & 0xFFFFFFu;
                if (r >= r0 && r < r1) {
                    float sc = attS[(size_t)s * R + r] + attD[(size_t)wv * R + r];
                    sc = sc > 0.f ? sc : NEG_SLOPE * sc;
                    float aa = __expf(sc - m) * inv;
                    unsigned row = (unsigned)((r - r0) * N) + s;
                    ushort8v v = *(const ushort8v*)&hWb[((size_t)row << 6) + dgrp * 8];
#pragma unroll
                    for (int j = 0; j < 8; j++) acc8[j] = fmaf(aa, bf2f(v[j]), acc8[j]);
                }
            }
        }
#pragma unroll
        for (int msk = 8; msk <= 32; msk <<= 1)
#pragma unroll
            for (int j = 0; j < 8; j++) acc8[j] += __shfl_xor(acc8[j], msk);
    }

    if (last) {
#pragma unroll
        for (int j = 0; j < 8; j++)
            acc8[j] = acc8[j] > 0.f ? acc8[j] : (__expf(acc8[j]) - 1.f);
        if (egrp == 0) {
            if (hbOut) {
                ushort4 o0, o1;
                o0.x = f2bf(acc8[0]); o0.y = f2bf(acc8[1]); o0.z = f2bf(acc8[2]); o0.w = f2bf(acc8[3]);
                o1.x = f2bf(acc8[4]); o1.y = f2bf(acc8[5]); o1.z = f2bf(acc8[6]); o1.w = f2bf(acc8[7]);
                *(ushort4*)&hbOut[(size_t)wv * 64 + dgrp * 8] = o0;
                *(ushort4*)&hbOut[(size_t)wv * 64 + dgrp * 8 + 4] = o1;
            } else {
                float4 v0 = {acc8[0], acc8[1], acc8[2], acc8[3]};
                float4 v1 = {acc8[4], acc8[5], acc8[6], acc8[7]};
                *(float4*)&agg[(size_t)wv * 64 + dgrp * 8] = v0;
                *(float4*)&agg[(size_t)wv * 64 + dgrp * 8 + 4] = v1;
            }
        }
    } else if (egrp == 0) {
        float4 v0 = {acc8[0], acc8[1], acc8[2], acc8[3]};
        float4 v1 = {acc8[4], acc8[5], acc8[6], acc8[7]};
        *(float4*)&agg[(size_t)wv * 64 + dgrp * 8] = v0;
        *(float4*)&agg[(size_t)wv * 64 + dgrp * 8 + 4] = v1;
    }
}

// ================= pooling / readout =================
__global__ void seg_sum64_kernel(const float* __restrict__ h, const int* __restrict__ seg,
                                 float* __restrict__ out, int N) {
    int i = blockIdx.x * blockDim.x + threadIdx.x;
    if (i >= N * 64) return;
    int n = i >> 6, d = i & 63;
    atomAddF(&out[seg[n] * 64 + d], h[i]);
}

__global__ void readout_kernel(const float* __restrict__ molr, const float* __restrict__ mol,
                               const int* __restrict__ mol2rxn, float* __restrict__ feat, int M) {
    int i = blockIdx.x * blockDim.x + threadIdx.x;
    if (i >= M * 64) return;
    int m = i >> 6, d = i & 63;
    int b = mol2rxn[m];
    atomAddF(&feat[b * 128 + d], molr[i]);
    atomAddF(&feat[b * 128 + 64 + d], mol[i]);
}

// ================= MLP head: LDS-tiled GEMM =================
#define APAD 36
__global__ __launch_bounds__(256) void fc_gemm_kernel(
        const float* __restrict__ A, const float* __restrict__ B,
        const float* __restrict__ bias, const float* __restrict__ prelu,
        float* __restrict__ C, int M, int N, int K, int mode) {
    __shared__ float Al[64 * APAD];
    __shared__ float Bl[32 * 64];
    int t = threadIdx.x;
    int n0 = blockIdx.x * 64, m0 = blockIdx.y * 64;
    int e4 = (t & 15) * 4;
    int n4 = (t >> 4) * 4;
    float acc[4][4] = {};

    for (int k0 = 0; k0 < K; k0 += 32) {
        {
            const float4* Ag = (const float4*)A;
#pragma unroll
            for (int i = 0; i < 2; i++) {
                int idx = t + i * 256;
                int row = idx >> 3, c4 = idx & 7;
                float4 v = Ag[(size_t)(m0 + row) * (K >> 2) + (k0 >> 2) + c4];
                float* p = &Al[row * APAD + c4 * 4];
                p[0] = v.x; p[1] = v.y; p[2] = v.z; p[3] = v.w;
            }
        }
        {
#pragma unroll
            for (int i = 0; i < 2; i++) {
                int idx = t + i * 256;
                int kk = idx >> 4, c4 = (idx & 15) * 4;
                int col = n0 + c4;
                float4 v;
                const float* Brow = B + (size_t)(k0 + kk) * N;
                if (col + 3 < N) v = *(const float4*)&Brow[col];
                else {
                    v.x = (col + 0 < N) ? Brow[col + 0] : 0.f;
                    v.y = (col + 1 < N) ? Brow[col + 1] : 0.f;
                    v.z = (col + 2 < N) ? Brow[col + 2] : 0.f;
                    v.w = 0.f;
                }
                *(float4*)&Bl[kk * 64 + c4] = v;
            }
        }
        __syncthreads();
        for (int d = 0; d < 32; d += 4) {
            float4 wv[4], hv[4];
#pragma unroll
            for (int dd = 0; dd < 4; dd++) wv[dd] = *(const float4*)&Bl[(d + dd) * 64 + e4];
#pragma unroll
            for (int i = 0; i < 4; i++) hv[i] = *(const float4*)&Al[(n4 + i) * APAD + d];
#pragma unroll
            for (int i = 0; i < 4; i++) {
                const float hvv[4] = {hv[i].x, hv[i].y, hv[i].z, hv[i].w};
#pragma unroll
                for (int dd = 0; dd < 4; dd++) {
                    const float* wp = (const float*)&wv[dd];
#pragma unroll
                    for (int j = 0; j < 4; j++) acc[i][j] = fmaf(hvv[dd], wp[j], acc[i][j]);
                }
            }
        }
        __syncthreads();
    }

    float p = mode ? *prelu : 0.f;
#pragma unroll
    for (int i = 0; i < 4; i++) {
        int row = m0 + n4 + i;
#pragma unroll
        for (int j = 0; j < 4; j++) {
            int col = n0 + e4 + j;
            if (col < N) {
                float v = acc[i][j] + bias[col];
                if (mode) v = v > 0.f ? v : p * v;
                C[(size_t)row * N + col] = v;
            }
        }
    }
}

// ================= launch =================
extern "C" void kernel_launch(void* const* d_in, const int* in_sizes, int n_in,
                              void* d_out, int out_size, void* d_ws, size_t ws_size,
                              hipStream_t stream) {
    const float* node_feats = (const float*)d_in[0];
    const int*   edge_src   = (const int*)d_in[1];
    const int*   edge_dst   = (const int*)d_in[2];
    const int*   edge_rel   = (const int*)d_in[3];
    const int*   node2mol   = (const int*)d_in[4];
    const int*   rxn_src    = (const int*)d_in[5];
    const int*   rxn_dst    = (const int*)d_in[6];
    const int*   rxn_rel    = (const int*)d_in[7];
    const int*   mol2rxn    = (const int*)d_in[8];
    const float* W1     = (const float*)d_in[9];
    const float* a_src1 = (const float*)d_in[10];
    const float* a_dst1 = (const float*)d_in[11];
    const float* W2     = (const float*)d_in[12];
    const float* a_src2 = (const float*)d_in[13];
    const float* a_dst2 = (const float*)d_in[14];
    const float* Wr     = (const float*)d_in[15];
    const float* a_srcr = (const float*)d_in[16];
    const float* a_dstr = (const float*)d_in[17];
    const float* w_fc1  = (const float*)d_in[18];
    const float* b_fc1  = (const float*)d_in[19];
    const float* prelu1 = (const float*)d_in[20];
    const float* w_fc2  = (const float*)d_in[21];
    const float* b_fc2  = (const float*)d_in[22];

    const int N = 100000, E = 800000, M = 5000, ER = 40000;

    float* ws = (float*)d_ws;
    unsigned short* hb1 = (unsigned short*)ws;        // 6.4M ush (layer-1 h, bf16)
    float* h2     = (float*)(hb1 + 6400000);          // 6.4M f (layer-2 out; also L1 carry scratch)
    float* attS   = h2 + 6400000;                     // 800K
    float* attD   = attS + 800000;                    // 800K
    float* mol    = attD + 800000;                    // 320K
    float* molr   = mol + 320000;                     // 320K
    float* feat   = molr + 320000;                    // 131072
    float* hm     = feat + 131072;                    // 524288
    unsigned short* Vbpad = (unsigned short*)(hm + 524288);  // 8*16*64 = 8192 ush
    int* rowptr   = (int*)(Vbpad + 8192);             // 100008
    int* bcnt     = rowptr + 100008;                  // 256
    int* bbase    = bcnt + 256;                       // 260
    int* bcursor  = bbase + 260;                      // 256
    unsigned* bpacked = (unsigned*)(bcursor + 256);   // 800000
    unsigned* packed  = bpacked + 800000;             // 800000
    unsigned short* hWb = (unsigned short*)(packed + 800000); // bf16 hW (chunked)

    size_t usedBytes = (size_t)((char*)hWb - (char*)d_ws);
    size_t availUshorts = (ws_size > usedBytes) ? (ws_size - usedBytes) / 2 : 0;

    auto buildCSR = [&](const int* dstArr, const int* srcArr, const int* relArr, int n, int e) {
        int NB = (n + 511) / 512;
        hipMemsetAsync(bcnt, 0, (size_t)NB * sizeof(int), stream);
        bhist_kernel<<<dim3(256), 256, 0, stream>>>(dstArr, bcnt, e);
        bscan_kernel<<<dim3(1), 256, 0, stream>>>(bcnt, bbase, bcursor, NB, rowptr, n, e);
        bpart_kernel<<<dim3((e + 4095) / 4096), 256, 0, stream>>>(dstArr, relArr, srcArr, bcursor, bpacked, e, NB);
        bsort_kernel<<<dim3(NB), 256, 0, stream>>>(bpacked, bbase, rowptr, packed, n);
    };

    auto rgat = [&](const void* hin, int hBf16, int n,
                    const float* W, const float* as, const float* ad,
                    float* agg, unsigned short* hbOut, int R) {
        hipMemsetAsync(Vbpad, 0, (size_t)R * 1024 * 2, stream);
        compute_v_kernel<<<dim3((R * 64 + 63) / 64), 64, 0, stream>>>(W, as, ad, Vbpad, R);

        size_t perRel = (size_t)n * 64;   // ushorts per relation
        int chunk = (int)(availUshorts / perRel);
        if (chunk < 1) chunk = 1;
        if (chunk > R) chunk = R;
        int fused = (chunk == R) ? 1 : 0;
        if (!fused)
            att_fallback_kernel<<<dim3((n * R + 255) / 256), 256, 0, stream>>>(
                hin, hBf16, Vbpad, attS, attD, n, R);
        for (int r0 = 0; r0 < R; r0 += chunk) {
            int r1 = r0 + chunk; if (r1 > R) r1 = R;
            hw_gemm_mfma_kernel<<<dim3((n + 63) / 64), 256, 0, stream>>>(
                hin, hBf16, W, Vbpad, hWb, attS, attD, n, R, r0, r1, fused);
            aggsoft_kernel<<<dim3(((size_t)n * 64 + 255) / 256), 256, 0, stream>>>(
                rowptr, packed, attS, attD, hWb, agg, hbOut, n, n, R, r0, r1, r1 == R ? 1 : 0);
        }
    };

    // ---- atom graph ----
    buildCSR(edge_dst, edge_src, edge_rel, N, E);
    // layer 1: fp32 input -> bf16 output (h2 used as fp32 carry scratch if chunked)
    rgat(node_feats, 0, N, W1, a_src1, a_dst1, h2, hb1, 8);
    // layer 2: bf16 input -> fp32 output h2
    rgat(hb1, 1, N, W2, a_src2, a_dst2, h2, nullptr, 8);

    // ---- molecule pooling ----
    hipMemsetAsync(mol, 0, (size_t)M * 64 * sizeof(float), stream);
    seg_sum64_kernel<<<dim3(((size_t)N * 64 + 255) / 256), 256, 0, stream>>>(h2, node2mol, mol, N);

    // ---- reaction-graph RGAT ----
    buildCSR(rxn_dst, rxn_src, rxn_rel, M, ER);
    rgat(mol, 0, M, Wr, a_srcr, a_dstr, molr, nullptr, 4);

    // ---- reaction readout ----
    hipMemsetAsync(feat, 0, (size_t)1024 * 128 * sizeof(float), stream);
    readout_kernel<<<dim3(((size_t)M * 64 + 255) / 256), 256, 0, stream>>>(molr, mol, mol2rxn, feat, M);

    // ---- MLP head: tiled GEMMs ----
    fc_gemm_kernel<<<dim3(8, 16), 256, 0, stream>>>(feat, w_fc1, b_fc1, prelu1, hm, 1024, 512, 128, 1);
    fc_gemm_kernel<<<dim3(11, 16), 256, 0, stream>>>(hm, w_fc2, b_fc2, nullptr, (float*)d_out, 1024, 703, 512, 0);
}